// Round 2
// baseline (441.673 us; speedup 1.0000x reference)
//
#include <hip/hip_runtime.h>
#include <cstdint>
#include <cstddef>

typedef unsigned short u16;
typedef __attribute__((ext_vector_type(8))) short bf16x8;
typedef __attribute__((ext_vector_type(4))) float f32x4;

// ---------- bf16 helpers ----------
__device__ __forceinline__ float b2f(u16 u) {
  union { uint32_t i; float f; } x; x.i = ((uint32_t)u) << 16; return x.f;
}
__device__ __forceinline__ u16 f2b(float f) {
  union { float f; uint32_t i; } x; x.f = f;
  uint32_t u = x.i;
  u += 0x7fffu + ((u >> 16) & 1u);   // RNE
  return (u16)(u >> 16);
}

// load 8 consecutive elements (idx multiple of 8) as float, dtype-branched
__device__ __forceinline__ void load8(const void* p, size_t idx, bool f32, float o[8]) {
  if (f32) {
    const float4* fp = (const float4*)((const float*)p + idx);
    float4 x = fp[0], y = fp[1];
    o[0] = x.x; o[1] = x.y; o[2] = x.z; o[3] = x.w;
    o[4] = y.x; o[5] = y.y; o[6] = y.z; o[7] = y.w;
  } else {
    uint4 w = *(const uint4*)((const u16*)p + idx);
    uint32_t ww[4] = {w.x, w.y, w.z, w.w};
#pragma unroll
    for (int q = 0; q < 4; q++) {
      o[2 * q]     = b2f((u16)(ww[q] & 0xffffu));
      o[2 * q + 1] = b2f((u16)(ww[q] >> 16));
    }
  }
}
__device__ __forceinline__ void store8_bf16(u16* p, size_t idx, const float o[8]) {
  uint32_t w[4];
#pragma unroll
  for (int q = 0; q < 4; q++)
    w[q] = (uint32_t)f2b(o[2 * q]) | ((uint32_t)f2b(o[2 * q + 1]) << 16);
  *(uint4*)(p + idx) = make_uint4(w[0], w[1], w[2], w[3]);
}

#define GLD_LDS16(gptr, lptr)                                                          \
  __builtin_amdgcn_global_load_lds((const __attribute__((address_space(1))) void*)(gptr), \
                                   (__attribute__((address_space(3))) void*)(lptr), 16, 0, 0)

// ---------- dtype detect: bf16-interpret first 1024 u16 of l; N(0,1) bf16 stays small,
// f32 mantissa halves blow up / NaN with probability ~1 ----------
__global__ __launch_bounds__(64)
void detect_k(const u16* __restrict__ lbits, int* __restrict__ flag)
{
  const int tid = threadIdx.x;
  int bad = 0;
  for (int i = tid; i < 1024; i += 64) {
    float f = b2f(lbits[i]);
    float af = fabsf(f);
    if (!(af <= 1.0e4f)) bad = 1;   // catches NaN too
  }
  int any = __any(bad);
  if (tid == 0) *flag = any ? 1 : 0;
}

// ---------- weight transpose: Wt[n][k] = W[k][n] (bf16), 5 matrices of 512x512 ----------
__global__ __launch_bounds__(1024)
void transw_k(const void* __restrict__ fc1W, const void* __restrict__ convW,
              u16* __restrict__ Wt, const int* __restrict__ flagp)
{
  const bool f32 = (*flagp != 0);
  __shared__ u16 tile[32][33];
  const int w = blockIdx.z;
  const void* W = (w == 0) ? fc1W : convW;
  const size_t base = (w == 0) ? 0 : (size_t)(w - 1) * 262144;
  const int tx = threadIdx.x, ty = threadIdx.y;
  const size_t i = base + (size_t)(blockIdx.y * 32 + ty) * 512 + (blockIdx.x * 32 + tx);
  float val = f32 ? ((const float*)W)[i] : b2f(((const u16*)W)[i]);
  tile[ty][tx] = f2b(val);
  __syncthreads();
  const int n_out = blockIdx.x * 32 + ty;
  const int k_out = blockIdx.y * 32 + tx;
  Wt[(size_t)w * 262144 + (size_t)n_out * 512 + k_out] = tile[tx][ty];
}

// ---------- feats: node-major bf16 `feat` + d_out cols [0,512) ----------
// node r = d*120 + mod*40 + t ; out row u = d*40+t, col base mod*1536
__global__ __launch_bounds__(256)
void feats_k(const void* __restrict__ a, const void* __restrict__ v, const void* __restrict__ l,
             const void* __restrict__ qmask, const void* __restrict__ spk,
             u16* __restrict__ feat, void* __restrict__ outv, const int* __restrict__ flagp)
{
  const bool f32 = (*flagp != 0);
  const int r  = blockIdx.x * 4 + (threadIdx.x >> 6);
  const int c0 = (threadIdx.x & 63) * 8;
  const int dm = r / 40;            // d*3 + mod
  const int t  = r - dm * 40;
  const int mod = dm % 3;
  const int d   = dm / 3;
  const int u   = d * 40 + t;
  float vals[8];
  const void* src = (mod == 1) ? a : ((mod == 2) ? v : l);
  load8(src, (size_t)u * 512 + c0, f32, vals);
  if (mod == 0) {
    const int qi = (t * 128 + d) * 2;
    float q0 = f32 ? ((const float*)qmask)[qi]     : b2f(((const u16*)qmask)[qi]);
    float q1 = f32 ? ((const float*)qmask)[qi + 1] : b2f(((const u16*)qmask)[qi + 1]);
    const int sidx = (q1 > q0) ? 1 : 0;     // np.argmax tie -> first index
    float sv[8];
    load8(spk, (size_t)sidx * 512 + c0, f32, sv);
#pragma unroll
    for (int j = 0; j < 8; j++) vals[j] += sv[j];
  }
  store8_bf16(feat, (size_t)r * 512 + c0, vals);
  const size_t oidx = (size_t)u * 4608 + mod * 1536 + c0;
  if (f32) {
    float4 x = make_float4(vals[0], vals[1], vals[2], vals[3]);
    float4 y = make_float4(vals[4], vals[5], vals[6], vals[7]);
    float4* op = (float4*)((float*)outv + oidx);
    op[0] = x; op[1] = y;
  } else {
    store8_bf16((u16*)outv, oidx, vals);
  }
}

// ---------- column sums per (dialogue,modality) block over fp32 g ----------
__global__ __launch_bounds__(256)
void colsum_k(const float* __restrict__ g, float* __restrict__ Bsum)
{
  const int blk = blockIdx.x;            // 0..383 = d*3+mod
  const int c0  = threadIdx.x * 2;
  const float* p = g + (size_t)blk * 40 * 512 + c0;
  float s0 = 0.f, s1 = 0.f;
#pragma unroll
  for (int t = 0; t < 40; t++) {
    float2 w = *(const float2*)(p + (size_t)t * 512);
    s0 += w.x; s1 += w.y;
  }
  Bsum[(size_t)blk * 512 + c0]     = s0;
  Bsum[(size_t)blk * 512 + c0 + 1] = s1;
}

// ---------- agg[r][c] = (Bsum[dm][c] + g[n1][c] + g[n2][c]) / 42 -> bf16 ----------
__global__ __launch_bounds__(256)
void agg_k(const float* __restrict__ g, const float* __restrict__ Bsum,
           u16* __restrict__ agg)
{
  const int r  = blockIdx.x * 4 + (threadIdx.x >> 6);
  const int c0 = (threadIdx.x & 63) * 8;
  const int dm = r / 40;
  const int t  = r - dm * 40;
  const int mod = dm % 3;
  const int d3  = dm - mod;             // d*3
  const int m1 = (mod == 0) ? 1 : 0;
  const int m2 = (mod == 2) ? 1 : 2;
  const float* p1 = g + ((size_t)(d3 + m1) * 40 + t) * 512 + c0;
  const float* p2 = g + ((size_t)(d3 + m2) * 40 + t) * 512 + c0;
  const float* bs = Bsum + (size_t)dm * 512 + c0;
  const float inv42 = 1.0f / 42.0f;
  float o[8];
#pragma unroll
  for (int q = 0; q < 2; q++) {
    float4 x1 = ((const float4*)p1)[q];
    float4 x2 = ((const float4*)p2)[q];
    float4 bb = ((const float4*)bs)[q];
    o[4*q+0] = (bb.x + x1.x + x2.x) * inv42;
    o[4*q+1] = (bb.y + x1.y + x2.y) * inv42;
    o[4*q+2] = (bb.z + x1.z + x2.z) * inv42;
    o[4*q+3] = (bb.w + x1.w + x2.w) * inv42;
  }
  store8_bf16(agg, (size_t)r * 512 + c0, o);
}

// ---------- GEMM: C = [resid +] A(15360x512,bf16) @ Bt^T + bias ----------
// Bt is N-major bf16. 128x128 tile, BK=32, 256 thr (4 waves, 2x2 of 64x64).
// Cg (fp32, optional): row-major store. Cout (optional): scattered store at +outoff,
// dtype per flag.
__global__ __launch_bounds__(256)
void gemm_bt(const u16* __restrict__ A, const u16* __restrict__ Bt,
             const void* __restrict__ bias, int boff,
             const float* __restrict__ resid,
             float* __restrict__ Cg, void* __restrict__ Cout, int outoff,
             const int* __restrict__ flagp)
{
  const bool f32io = (*flagp != 0);
  __shared__ __align__(16) u16 As[128 * 32];
  __shared__ __align__(16) u16 Bs[128 * 32];
  const int tid  = threadIdx.x;
  const int lane = tid & 63;
  const int wave = tid >> 6;
  const int wm = wave & 1, wn = wave >> 1;
  const int quad = lane >> 4;
  const int l16  = lane & 15;
  const int tileM = blockIdx.x * 128;
  const int tileN = blockIdx.y * 128;

  // staging: thread stages chunks tid and tid+256 (16B each) for A and Bt
  const int ch0 = tid, ch1 = tid + 256;
  const int r0 = ch0 >> 2, c0 = (ch0 & 3) * 8;
  const int r1 = ch1 >> 2, c1 = (ch1 & 3) * 8;
  const size_t arow0 = (size_t)(tileM + r0) * 512;
  const size_t arow1 = (size_t)(tileM + r1) * 512;
  const size_t brow0 = (size_t)(tileN + r0) * 512;
  const size_t brow1 = (size_t)(tileN + r1) * 512;

  f32x4 acc[4][4];
#pragma unroll
  for (int i = 0; i < 4; i++)
#pragma unroll
    for (int j = 0; j < 4; j++) {
      f32x4 z = {0.f, 0.f, 0.f, 0.f};
      acc[i][j] = z;
    }

  for (int k0 = 0; k0 < 512; k0 += 32) {
    GLD_LDS16(A  + arow0 + k0 + c0, &As[ch0 * 8]);
    GLD_LDS16(A  + arow1 + k0 + c1, &As[ch1 * 8]);
    GLD_LDS16(Bt + brow0 + k0 + c0, &Bs[ch0 * 8]);
    GLD_LDS16(Bt + brow1 + k0 + c1, &Bs[ch1 * 8]);
    asm volatile("s_waitcnt vmcnt(0)" ::: "memory");
    __syncthreads();
    bf16x8 af[4], bv[4];
#pragma unroll
    for (int i = 0; i < 4; i++)
      af[i] = *(const bf16x8*)&As[(wm * 64 + i * 16 + l16) * 32 + quad * 8];
#pragma unroll
    for (int j = 0; j < 4; j++)
      bv[j] = *(const bf16x8*)&Bs[(wn * 64 + j * 16 + l16) * 32 + quad * 8];
#pragma unroll
    for (int i = 0; i < 4; i++)
#pragma unroll
      for (int j = 0; j < 4; j++)
        acc[i][j] = __builtin_amdgcn_mfma_f32_16x16x32_bf16(af[i], bv[j], acc[i][j], 0, 0, 0);
    __syncthreads();
  }

  // epilogue: C/D layout col = lane&15, row = quad*4 + reg
#pragma unroll
  for (int i = 0; i < 4; i++) {
    const int gmBase = tileM + wm * 64 + i * 16 + quad * 4;
#pragma unroll
    for (int r = 0; r < 4; r++) {
      const int gm = gmBase + r;
      size_t outRow = 0;
      if (Cout != nullptr) {
        int dd = gm / 120, md = gm - dd * 120, mm = md / 40, tt = md - mm * 40;
        outRow = (size_t)(dd * 40 + tt) * 4608 + mm * 1536 + outoff;
      }
#pragma unroll
      for (int j = 0; j < 4; j++) {
        const int gn = tileN + wn * 64 + j * 16 + l16;
        float bval = f32io ? ((const float*)bias)[boff + gn] : b2f(((const u16*)bias)[boff + gn]);
        float vsum = acc[i][j][r] + bval;
        if (resid != nullptr) vsum += resid[(size_t)gm * 512 + gn];
        if (Cg != nullptr) Cg[(size_t)gm * 512 + gn] = vsum;
        if (Cout != nullptr) {
          if (f32io) ((float*)Cout)[outRow + gn] = vsum;
          else       ((u16*)Cout)[outRow + gn] = f2b(vsum);
        }
      }
    }
  }
}

// ---------- launch ----------
extern "C" void kernel_launch(void* const* d_in, const int* in_sizes, int n_in,
                              void* d_out, int out_size, void* d_ws, size_t ws_size,
                              hipStream_t stream)
{
  const void* a     = d_in[0];
  const void* v     = d_in[1];
  const void* l     = d_in[2];
  const void* qmask = d_in[3];
  const void* spk   = d_in[4];
  const void* fc1W  = d_in[5];
  const void* fc1b  = d_in[6];
  const void* convW = d_in[7];
  const void* convb = d_in[8];

  char* ws = (char*)d_ws;
  u16*   Wt   = (u16*)(ws);                       // 5*512*512*2   =  2,621,440 B
  u16*   feat = (u16*)(ws + 2621440);             // 15360*512*2   = 15,728,640 B
  float* g    = (float*)(ws + 18350080);          // 15360*512*4   = 31,457,280 B
  u16*   agg  = (u16*)(ws + 49807360);            // 15360*512*2   = 15,728,640 B
  float* Bsum = (float*)(ws + 65536000);          // 384*512*4     =    786,432 B
  int*   flag = (int*)(ws + 66322432);            // 4 B ; total ~66.3 MB

  // 0) detect input dtype (bf16 vs f32) from raw bits of l
  detect_k<<<1, 64, 0, stream>>>((const u16*)l, flag);

  // 1) transpose weights (fc1 + 4 conv layers) to N-major bf16
  transw_k<<<dim3(16, 16, 5), dim3(32, 32), 0, stream>>>(fc1W, convW, Wt, flag);

  // 2) feats -> bf16 `feat` (node-major) and d_out cols [0,512)
  feats_k<<<3840, 256, 0, stream>>>(a, v, l, qmask, spk, feat, d_out, flag);

  // 3) x1 = feats @ fc1W + fc1b -> g (fp32 row-major) and d_out cols [512,1024)
  gemm_bt<<<dim3(120, 4), 256, 0, stream>>>(feat, Wt, fc1b, 0, nullptr, g, d_out, 512, flag);

  // 4) four GCN layers: g += agg(g) @ Wk + bk ; last layer -> d_out cols [1024,1536)
  for (int k = 0; k < 4; k++) {
    colsum_k<<<384, 256, 0, stream>>>(g, Bsum);
    agg_k<<<3840, 256, 0, stream>>>(g, Bsum, agg);
    const bool last = (k == 3);
    gemm_bt<<<dim3(120, 4), 256, 0, stream>>>(
        agg, Wt + (size_t)(k + 1) * 262144, convb, k * 512,
        g, last ? nullptr : g, last ? d_out : nullptr, 1024, flag);
  }
}

// Round 3
// 370.595 us; speedup vs baseline: 1.1918x; 1.1918x over previous
//
#include <hip/hip_runtime.h>
#include <cstdint>
#include <cstddef>

typedef unsigned short u16;
typedef __attribute__((ext_vector_type(8))) short bf16x8;
typedef __attribute__((ext_vector_type(4))) float f32x4;

// ---------- bf16 helpers ----------
__device__ __forceinline__ float b2f(u16 u) {
  union { uint32_t i; float f; } x; x.i = ((uint32_t)u) << 16; return x.f;
}
__device__ __forceinline__ u16 f2b(float f) {
  union { float f; uint32_t i; } x; x.f = f;
  uint32_t u = x.i;
  u += 0x7fffu + ((u >> 16) & 1u);   // RNE
  return (u16)(u >> 16);
}

// load 8 consecutive elements (idx multiple of 8) as float, dtype-branched
__device__ __forceinline__ void load8(const void* p, size_t idx, bool f32, float o[8]) {
  if (f32) {
    const float4* fp = (const float4*)((const float*)p + idx);
    float4 x = fp[0], y = fp[1];
    o[0] = x.x; o[1] = x.y; o[2] = x.z; o[3] = x.w;
    o[4] = y.x; o[5] = y.y; o[6] = y.z; o[7] = y.w;
  } else {
    uint4 w = *(const uint4*)((const u16*)p + idx);
    uint32_t ww[4] = {w.x, w.y, w.z, w.w};
#pragma unroll
    for (int q = 0; q < 4; q++) {
      o[2 * q]     = b2f((u16)(ww[q] & 0xffffu));
      o[2 * q + 1] = b2f((u16)(ww[q] >> 16));
    }
  }
}
__device__ __forceinline__ void store8_bf16(u16* p, size_t idx, const float o[8]) {
  uint32_t w[4];
#pragma unroll
  for (int q = 0; q < 4; q++)
    w[q] = (uint32_t)f2b(o[2 * q]) | ((uint32_t)f2b(o[2 * q + 1]) << 16);
  *(uint4*)(p + idx) = make_uint4(w[0], w[1], w[2], w[3]);
}

#define GLD_LDS16(gptr, lptr)                                                          \
  __builtin_amdgcn_global_load_lds((const __attribute__((address_space(1))) void*)(gptr), \
                                   (__attribute__((address_space(3))) void*)(lptr), 16, 0, 0)

// ---------- dtype detect (bf16 vs f32 inputs) from raw bits of l ----------
__global__ __launch_bounds__(64)
void detect_k(const u16* __restrict__ lbits, int* __restrict__ flag)
{
  const int tid = threadIdx.x;
  int bad = 0;
  for (int i = tid; i < 1024; i += 64) {
    float f = b2f(lbits[i]);
    float af = fabsf(f);
    if (!(af <= 1.0e4f)) bad = 1;   // catches NaN too
  }
  int any = __any(bad);
  if (tid == 0) *flag = any ? 1 : 0;
}

// ---------- weight transpose: Wt[n][k] = W[k][n] (bf16), 5 matrices of 512x512 ----------
__global__ __launch_bounds__(1024)
void transw_k(const void* __restrict__ fc1W, const void* __restrict__ convW,
              u16* __restrict__ Wt, const int* __restrict__ flagp)
{
  const bool f32 = (*flagp != 0);
  __shared__ u16 tile[32][33];
  const int w = blockIdx.z;
  const void* W = (w == 0) ? fc1W : convW;
  const size_t base = (w == 0) ? 0 : (size_t)(w - 1) * 262144;
  const int tx = threadIdx.x, ty = threadIdx.y;
  const size_t i = base + (size_t)(blockIdx.y * 32 + ty) * 512 + (blockIdx.x * 32 + tx);
  float val = f32 ? ((const float*)W)[i] : b2f(((const u16*)W)[i]);
  tile[ty][tx] = f2b(val);
  __syncthreads();
  const int n_out = blockIdx.x * 32 + ty;
  const int k_out = blockIdx.y * 32 + tx;
  Wt[(size_t)w * 262144 + (size_t)n_out * 512 + k_out] = tile[tx][ty];
}

// ---------- feats: node-major bf16 `feat` + d_out cols [0,512) ----------
// node r = d*120 + mod*40 + t ; out row u = d*40+t, col base mod*1536
__global__ __launch_bounds__(256)
void feats_k(const void* __restrict__ a, const void* __restrict__ v, const void* __restrict__ l,
             const void* __restrict__ qmask, const void* __restrict__ spk,
             u16* __restrict__ feat, void* __restrict__ outv, const int* __restrict__ flagp)
{
  const bool f32 = (*flagp != 0);
  const int r  = blockIdx.x * 4 + (threadIdx.x >> 6);
  const int c0 = (threadIdx.x & 63) * 8;
  const int dm = r / 40;            // d*3 + mod
  const int t  = r - dm * 40;
  const int mod = dm % 3;
  const int d   = dm / 3;
  const int u   = d * 40 + t;
  float vals[8];
  const void* src = (mod == 1) ? a : ((mod == 2) ? v : l);
  load8(src, (size_t)u * 512 + c0, f32, vals);
  if (mod == 0) {
    const int qi = (t * 128 + d) * 2;
    float q0 = f32 ? ((const float*)qmask)[qi]     : b2f(((const u16*)qmask)[qi]);
    float q1 = f32 ? ((const float*)qmask)[qi + 1] : b2f(((const u16*)qmask)[qi + 1]);
    const int sidx = (q1 > q0) ? 1 : 0;     // np.argmax tie -> first index
    float sv[8];
    load8(spk, (size_t)sidx * 512 + c0, f32, sv);
#pragma unroll
    for (int j = 0; j < 8; j++) vals[j] += sv[j];
  }
  store8_bf16(feat, (size_t)r * 512 + c0, vals);
  const size_t oidx = (size_t)u * 4608 + mod * 1536 + c0;
  if (f32) {
    float4* op = (float4*)((float*)outv + oidx);
    op[0] = make_float4(vals[0], vals[1], vals[2], vals[3]);
    op[1] = make_float4(vals[4], vals[5], vals[6], vals[7]);
  } else {
    store8_bf16((u16*)outv, oidx, vals);
  }
}

// ---------- column sums per (dialogue,modality) block over bf16 gb ----------
// grid 96 x 256: thread = (dm = bid*4 + tid>>6, cols (tid&63)*8 .. +7)
__global__ __launch_bounds__(256)
void colsum_k(const u16* __restrict__ gb, float* __restrict__ Bsum)
{
  const int dm = blockIdx.x * 4 + (threadIdx.x >> 6);
  const int c0 = (threadIdx.x & 63) * 8;
  const u16* p = gb + (size_t)dm * 40 * 512 + c0;
  float s[8] = {0.f, 0.f, 0.f, 0.f, 0.f, 0.f, 0.f, 0.f};
#pragma unroll
  for (int t = 0; t < 40; t++) {
    uint4 w = *(const uint4*)(p + (size_t)t * 512);
    uint32_t ww[4] = {w.x, w.y, w.z, w.w};
#pragma unroll
    for (int q = 0; q < 4; q++) {
      s[2 * q]     += b2f((u16)(ww[q] & 0xffffu));
      s[2 * q + 1] += b2f((u16)(ww[q] >> 16));
    }
  }
  float4* bp = (float4*)(Bsum + (size_t)dm * 512 + c0);
  bp[0] = make_float4(s[0], s[1], s[2], s[3]);
  bp[1] = make_float4(s[4], s[5], s[6], s[7]);
}

// ---------- agg[r][c] = (Bsum[dm][c] + gb[n1][c] + gb[n2][c]) / 42 -> bf16 ----------
__global__ __launch_bounds__(256)
void agg_k(const u16* __restrict__ gb, const float* __restrict__ Bsum,
           u16* __restrict__ agg)
{
  const int r  = blockIdx.x * 4 + (threadIdx.x >> 6);
  const int c0 = (threadIdx.x & 63) * 8;
  const int dm = r / 40;
  const int t  = r - dm * 40;
  const int mod = dm % 3;
  const int d3  = dm - mod;             // d*3
  const int m1 = (mod == 0) ? 1 : 0;
  const int m2 = (mod == 2) ? 1 : 2;
  const u16* p1 = gb + ((size_t)(d3 + m1) * 40 + t) * 512 + c0;
  const u16* p2 = gb + ((size_t)(d3 + m2) * 40 + t) * 512 + c0;
  const float* bs = Bsum + (size_t)dm * 512 + c0;
  uint4 u1 = *(const uint4*)p1;
  uint4 u2 = *(const uint4*)p2;
  uint32_t w1[4] = {u1.x, u1.y, u1.z, u1.w};
  uint32_t w2[4] = {u2.x, u2.y, u2.z, u2.w};
  const float inv42 = 1.0f / 42.0f;
  float o[8];
#pragma unroll
  for (int q = 0; q < 4; q++) {
    float b0 = bs[2 * q], b1 = bs[2 * q + 1];
    o[2*q]   = (b0 + b2f((u16)(w1[q] & 0xffffu)) + b2f((u16)(w2[q] & 0xffffu))) * inv42;
    o[2*q+1] = (b1 + b2f((u16)(w1[q] >> 16))     + b2f((u16)(w2[q] >> 16)))     * inv42;
  }
  store8_bf16(agg, (size_t)r * 512 + c0, o);
}

// ---------- GEMM v2: C = [resid +] A(15360x512,bf16) @ Bt^T + bias ----------
// 512 threads = 8 waves (2 M x 4 N), wave tile 64x32, block tile 128x128, BK=32.
// Double-buffered LDS; prefetch k+1 issued after the single per-iter barrier so
// its latency hides under ds_read+MFMA of tile k.
__global__ __launch_bounds__(512, 4)
void gemm_bt(const u16* __restrict__ A, const u16* __restrict__ Bt,
             const void* __restrict__ bias, int boff,
             const float* __restrict__ resid,
             float* __restrict__ Cg, u16* __restrict__ Cgb,
             void* __restrict__ Cout, int outoff,
             const int* __restrict__ flagp)
{
  const bool f32io = (*flagp != 0);
  __shared__ __align__(16) u16 As[2][128 * 32];
  __shared__ __align__(16) u16 Bs[2][128 * 32];
  const int tid  = threadIdx.x;       // 0..511
  const int lane = tid & 63;
  const int wave = tid >> 6;          // 0..7
  const int wm = wave >> 2;           // 0..1  (64-row M group)
  const int wn = wave & 3;            // 0..3  (32-col N group)
  const int quad = lane >> 4;
  const int l16  = lane & 15;
  const int tileM = blockIdx.x * 128;
  const int tileN = blockIdx.y * 128;

  // staging: one 16B chunk per thread per matrix (128 rows x 32 k = 512 chunks)
  const int r0 = tid >> 2, c0 = (tid & 3) * 8;
  const size_t arow = (size_t)(tileM + r0) * 512 + c0;
  const size_t brow = (size_t)(tileN + r0) * 512 + c0;

  f32x4 acc[4][2];
#pragma unroll
  for (int i = 0; i < 4; i++)
#pragma unroll
    for (int j = 0; j < 2; j++) {
      f32x4 z = {0.f, 0.f, 0.f, 0.f};
      acc[i][j] = z;
    }

  // prefetch K-chunk 0 into buffer 0
  GLD_LDS16(A  + arow, &As[0][tid * 8]);
  GLD_LDS16(Bt + brow, &Bs[0][tid * 8]);

  for (int kk = 0; kk < 16; kk++) {
    const int cur = kk & 1;
    asm volatile("s_waitcnt vmcnt(0)" ::: "memory");
    __syncthreads();                       // buf[cur] ready; buf[1-cur] free
    if (kk < 15) {
      const int k0 = (kk + 1) * 32;
      GLD_LDS16(A  + arow + k0, &As[1 - cur][tid * 8]);
      GLD_LDS16(Bt + brow + k0, &Bs[1 - cur][tid * 8]);
    }
    bf16x8 af[4], bv[2];
#pragma unroll
    for (int i = 0; i < 4; i++)
      af[i] = *(const bf16x8*)&As[cur][(wm * 64 + i * 16 + l16) * 32 + quad * 8];
#pragma unroll
    for (int j = 0; j < 2; j++)
      bv[j] = *(const bf16x8*)&Bs[cur][(wn * 32 + j * 16 + l16) * 32 + quad * 8];
#pragma unroll
    for (int i = 0; i < 4; i++)
#pragma unroll
      for (int j = 0; j < 2; j++)
        acc[i][j] = __builtin_amdgcn_mfma_f32_16x16x32_bf16(af[i], bv[j], acc[i][j], 0, 0, 0);
  }

  // epilogue: C/D layout col = lane&15, row = quad*4 + reg
#pragma unroll
  for (int i = 0; i < 4; i++) {
    const int gmBase = tileM + wm * 64 + i * 16 + quad * 4;
#pragma unroll
    for (int r = 0; r < 4; r++) {
      const int gm = gmBase + r;
      size_t outRow = 0;
      if (Cout != nullptr) {
        int dd = gm / 120, md = gm - dd * 120, mm = md / 40, tt = md - mm * 40;
        outRow = (size_t)(dd * 40 + tt) * 4608 + mm * 1536 + outoff;
      }
#pragma unroll
      for (int j = 0; j < 2; j++) {
        const int gn = tileN + wn * 32 + j * 16 + l16;
        float bval = f32io ? ((const float*)bias)[boff + gn] : b2f(((const u16*)bias)[boff + gn]);
        float vsum = acc[i][j][r] + bval;
        if (resid != nullptr) vsum += resid[(size_t)gm * 512 + gn];
        if (Cg  != nullptr) Cg[(size_t)gm * 512 + gn] = vsum;
        if (Cgb != nullptr) Cgb[(size_t)gm * 512 + gn] = f2b(vsum);
        if (Cout != nullptr) {
          if (f32io) ((float*)Cout)[outRow + gn] = vsum;
          else       ((u16*)Cout)[outRow + gn] = f2b(vsum);
        }
      }
    }
  }
}

// ---------- launch ----------
extern "C" void kernel_launch(void* const* d_in, const int* in_sizes, int n_in,
                              void* d_out, int out_size, void* d_ws, size_t ws_size,
                              hipStream_t stream)
{
  const void* a     = d_in[0];
  const void* v     = d_in[1];
  const void* l     = d_in[2];
  const void* qmask = d_in[3];
  const void* spk   = d_in[4];
  const void* fc1W  = d_in[5];
  const void* fc1b  = d_in[6];
  const void* convW = d_in[7];
  const void* convb = d_in[8];

  char* ws = (char*)d_ws;
  u16*   Wt   = (u16*)(ws);                       // 5*512*512*2   =  2,621,440 B
  u16*   feat = (u16*)(ws + 2621440);             // 15360*512*2   = 15,728,640 B
  float* g    = (float*)(ws + 18350080);          // 15360*512*4   = 31,457,280 B
  u16*   gb   = (u16*)(ws + 49807360);            // 15360*512*2   = 15,728,640 B
  u16*   agg  = (u16*)(ws + 65536000);            // 15360*512*2   = 15,728,640 B
  float* Bsum = (float*)(ws + 81264640);          // 384*512*4     =    786,432 B
  int*   flag = (int*)(ws + 82051072);            // 4 B ; total ~82 MB

  // 0) detect input dtype (bf16 vs f32) from raw bits of l
  detect_k<<<1, 64, 0, stream>>>((const u16*)l, flag);

  // 1) transpose weights (fc1 + 4 conv layers) to N-major bf16
  transw_k<<<dim3(16, 16, 5), dim3(32, 32), 0, stream>>>(fc1W, convW, Wt, flag);

  // 2) feats -> bf16 `feat` (node-major) and d_out cols [0,512)
  feats_k<<<3840, 256, 0, stream>>>(a, v, l, qmask, spk, feat, d_out, flag);

  // 3) x1 = feats @ fc1W + fc1b -> g (fp32), gb (bf16), d_out cols [512,1024)
  gemm_bt<<<dim3(120, 4), 512, 0, stream>>>(feat, Wt, fc1b, 0, nullptr,
                                            g, gb, d_out, 512, flag);

  // 4) four GCN layers: g += agg(g) @ Wk + bk ; last layer -> d_out cols [1024,1536)
  for (int k = 0; k < 4; k++) {
    colsum_k<<<96, 256, 0, stream>>>(gb, Bsum);
    agg_k<<<3840, 256, 0, stream>>>(gb, Bsum, agg);
    const bool last = (k == 3);
    gemm_bt<<<dim3(120, 4), 512, 0, stream>>>(
        agg, Wt + (size_t)(k + 1) * 262144, convb, k * 512,
        g, last ? nullptr : g, last ? nullptr : gb,
        last ? d_out : nullptr, 1024, flag);
  }
}